// Round 9
// baseline (133.081 us; speedup 1.0000x reference)
//
#include <hip/hip_runtime.h>

// Problem constants: T=1024, B=256, H=20
#define T_N 1024
#define B_N 256
#define H_N 20
#define NW  8            // waves per block
#define NDW (NW - 1)     // dot waves
#define SIH 1096         // I-history row stride in HALVES (conflict-free layout, see R5)
#define DPP_WAVE_SHR1 0x138

typedef _Float16 h8_t __attribute__((ext_vector_type(8)));

#if __has_builtin(__builtin_amdgcn_fdot2)
#define DOT8(acc, mv, iv)                                                           \
    acc = __builtin_amdgcn_fdot2(__builtin_shufflevector(mv, mv, 0, 1),             \
                                 __builtin_shufflevector(iv, iv, 0, 1), acc, false);\
    acc = __builtin_amdgcn_fdot2(__builtin_shufflevector(mv, mv, 2, 3),             \
                                 __builtin_shufflevector(iv, iv, 2, 3), acc, false);\
    acc = __builtin_amdgcn_fdot2(__builtin_shufflevector(mv, mv, 4, 5),             \
                                 __builtin_shufflevector(iv, iv, 4, 5), acc, false);\
    acc = __builtin_amdgcn_fdot2(__builtin_shufflevector(mv, mv, 6, 7),             \
                                 __builtin_shufflevector(iv, iv, 6, 7), acc, false);
#else
#define DOT8(acc, mv, iv)                                                           \
    _Pragma("unroll")                                                               \
    for (int _k = 0; _k < 8; ++_k) acc = fmaf((float)mv[_k], (float)iv[_k], acc);
#endif

__device__ __forceinline__ float rdlane_i(float v, int lane) {
    return __uint_as_float((unsigned)__builtin_amdgcn_readlane((int)__float_as_uint(v), lane));
}
__device__ __forceinline__ float fast_tanh(float x) {
    const float e = __expf(2.0f * x);
    return fmaf(-2.0f, __builtin_amdgcn_rcpf(e + 1.0f), 1.0f);
}
__device__ __forceinline__ float fast_sigmoid(float x) {
    return __builtin_amdgcn_rcpf(1.0f + __expf(-x));
}

// wave-wide shift-up-by-1 (lane L <- lane L-1), lane 0 <- 0
#if __has_builtin(__builtin_amdgcn_update_dpp)
__device__ __forceinline__ int shift1z(int v, int /*L*/) {
    return __builtin_amdgcn_update_dpp(0, v, DPP_WAVE_SHR1, 0xF, 0xF, false);
}
#else
__device__ __forceinline__ int shift1z(int v, int L) {
    const int s = __shfl_up(v, 1);
    return (L == 0) ? 0 : s;
}
#endif

// explicit literal-token repetition
#define REP64(F) \
    F(0) F(1) F(2) F(3) F(4) F(5) F(6) F(7) F(8) F(9) F(10) F(11) F(12) F(13) \
    F(14) F(15) F(16) F(17) F(18) F(19) F(20) F(21) F(22) F(23) F(24) F(25)   \
    F(26) F(27) F(28) F(29) F(30) F(31) F(32) F(33) F(34) F(35) F(36) F(37)   \
    F(38) F(39) F(40) F(41) F(42) F(43) F(44) F(45) F(46) F(47) F(48) F(49)   \
    F(50) F(51) F(52) F(53) F(54) F(55) F(56) F(57) F(58) F(59) F(60) F(61)   \
    F(62) F(63)

// ---------------------------------------------------------------------------
// Single fused kernel. 256 blocks (1/batch) x 512 threads (8 waves).
// Phase A: all waves compute me[1024] -> fp32 sMeF + fp16 sMeH.
// Phase B: wave 0 = serial SIR chain. The Toeplitz fold weights live in a
//          2-register 128-lane SHIFT CHAIN (g feeds h's lane 0 via
//          readlane + per-lane select) -> zero memory ops per step.
//          waves 1-7 = fp16 fdot2 history dots (conflict-free R5 layout).
// ---------------------------------------------------------------------------
__global__ __launch_bounds__(512, 1) void scan_kernel(
    const float* __restrict__ t,
    const float* __restrict__ y,
    const float* __restrict__ w1, const float* __restrict__ b1,
    const float* __restrict__ w2, const float* __restrict__ b2,
    const float* __restrict__ w3, const float* __restrict__ b3,
    const float* __restrict__ w4, const float* __restrict__ b4,
    const float* __restrict__ beta_p,
    const float* __restrict__ gamma_p,
    float* __restrict__ out)     // [solution (T*B*3) | diff (T*B*3)]
{
    __shared__ __align__(16) float    sMeF[T_N];      // fp32 me
    __shared__ __align__(16) _Float16 sMeH[T_N];      // fp16 me (dot operand A)
    __shared__ __align__(16) _Float16 sIhR[8 * SIH];  // 8 shifted fp16 I-history rows
    __shared__ float P[2][NDW][64];

    const int b   = blockIdx.x;
    const int tid = threadIdx.x;
    const int wid = tid >> 6;
    const int L   = tid & 63;

    // per-lane dot-geometry constants (chunk-invariant)
    const int f    = (-L) & 7;            // misalignment of lane L's me window
    const int R8   = L + f;               // L rounded up to multiple of 8
    const int row  = L & 7;               // I-history row for this lane
    const int iofs = row * SIH + (f ? 0 : 8);

    // zero the row front-pads (slots representing I[<0])
    if (tid < 64) sIhR[(tid >> 3) * SIH + (tid & 7)] = (_Float16)0.0f;

    // ---- Phase A: me MLP (2 values/thread) ----
#pragma unroll
    for (int v = 0; v < 2; ++v) {
        const int mi = tid + v * 512;
        const float x = t[mi];

        float h1[H_N], h2[H_N];
#pragma unroll
        for (int k = 0; k < H_N; ++k) h1[k] = fast_tanh(fmaf(x, w1[k], b1[k]));

#pragma unroll 4
        for (int k = 0; k < H_N; ++k) {
            float a = b2[k];
#pragma unroll
            for (int j = 0; j < H_N; ++j) a = fmaf(h1[j], w2[j * H_N + k], a);
            h2[k] = fast_tanh(a);
        }

        float a4 = b4[0];
#pragma unroll 4
        for (int k = 0; k < H_N; ++k) {
            float a = b3[k];
#pragma unroll
            for (int j = 0; j < H_N; ++j) a = fmaf(h2[j], w3[j * H_N + k], a);
            a4 = fmaf(fast_tanh(a), w4[k], a4);
        }

        const float meval = fast_sigmoid(a4);
        sMeF[mi] = meval;
        sMeH[mi] = (_Float16)meval;
    }

    // ---- scalars / state ----
    const float dt    = t[0] - t[1];
    const float beta  = beta_p[0];
    const float gma   = gamma_p[0];
    const float invdt = 1.0f / dt;

    const float S0 = y[b * 3 + 0];
    const float I0 = y[b * 3 + 1];
    const float R0 = y[b * 3 + 2];
    const float TOT = S0 + I0 + R0;     // SIR total conserved

    // publish I[0] into all 8 rows
    if (tid < 8) sIhR[tid * SIH + 8 - tid] = (_Float16)I0;

    float* __restrict__ diff = out + (size_t)T_N * B_N * 3;
    if (tid < 3) diff[((size_t)(T_N - 1) * B_N + b) * 3 + tid] = 0.0f;

    __syncthreads();   // sMeF/sMeH/pads/I0 visible

    // fixup me weights (chunk-invariant): mf[d-1] = me[960 - L - d]
    float mf[7];
#pragma unroll
    for (int d = 1; d <= 7; ++d) mf[d - 1] = sMeF[T_N - 64 - L - d];

    const float dtb  = dt * beta;
    const float ndtg = -dt * gma;
    const float dt2  = dt * dt;

    float S = S0, I = I0, oS = S0, oI = I0;
    float acc_cur = 0.0f, acc_nxt = 0.0f, sum = 0.0f;
    float carryS = S0, carryI = I0;
    const bool lane0 = (L == 0);

    // pristine shift-register seeds (2 VGPRs): g0[L]=me[T-L] (lane0=0),
    // h0[L]=me[T-64-L]. Weight at step m: g_m[L]=g0[L-m], h_m[L]=h0 delayed,
    // with g's lane-63 outflow injected into h's lane 0 each step.
    const int g0i = (L > 0) ? __float_as_int(sMeF[T_N - L]) : 0;
    const int h0i = __float_as_int(sMeF[T_N - 64 - L]);
    int gri = g0i, hri = h0i;

    // serial step M_: entering (S,I) = y_{64c+M_-1}; produces y_{64c+M_}.
    // `sum` (= acc_cur[M_] complete through fold M_-1) was read at the end of
    // the previous step, AFTER that step's fold -> no patch term needed.
#define STEPB(M_)                                                       \
    {                                                                   \
        const float bI = dtb * I;                                       \
        const float i1 = fmaf(ndtg, I, I);                              \
        const float q  = bI * S;                                        \
        const float s1 = S - q;                                         \
        S = fmaf(dt2, sum, s1);                                         \
        I = i1 + q;                                                     \
        const bool cap = (L == (M_));                                   \
        oS = cap ? S : oS;                                              \
        oI = cap ? I : oI;                                              \
        if ((M_) < 63) {                                                \
            const int inj = __builtin_amdgcn_readlane(gri, 63);         \
            acc_cur = fmaf(__int_as_float(gri), I, acc_cur);            \
            acc_nxt = fmaf(__int_as_float(hri), I, acc_nxt);            \
            sum = rdlane_i(acc_cur, (M_) + 1);                          \
            gri = shift1z(gri, L);                                      \
            const int hsh = shift1z(hri, L);                            \
            hri = lane0 ? inj : hsh;                                    \
        } else {                                                        \
            acc_nxt = fmaf(__int_as_float(hri), I, acc_nxt);            \
        }                                                               \
    }
#define STEP_GE1(M_) if ((M_) >= 1) STEPB(M_)

    for (int c = 0; c < 16; ++c) {
        if (wid == 0) {
            gri = g0i;
            hri = h0i;
            if (c == 0) {
                // fold m=0 (initial I0), then shift chain once
                const int inj = __builtin_amdgcn_readlane(gri, 63);
                acc_cur = __int_as_float(gri) * I;
                acc_nxt = __int_as_float(hri) * I;
                sum = rdlane_i(acc_cur, 1);
                gri = shift1z(gri, L);
                const int hsh = shift1z(hri, L);
                hri = lane0 ? inj : hsh;
                REP64(STEP_GE1)
            } else {
                float ac = acc_nxt;
#pragma unroll
                for (int w = 0; w < NDW; ++w) ac += P[c & 1][w][L];
                acc_cur = ac;
                acc_nxt = 0.0f;
                sum = rdlane_i(acc_cur, 0);
                REP64(STEPB)
            }

            // ---- chunk epilogue (wave 0) ----
            const int j = 64 * c + L;
            const _Float16 hI = (_Float16)oI;
#pragma unroll
            for (int r = 0; r < 8; ++r) sIhR[r * SIH + 8 + (j - r)] = hI;

            const float oR = TOT - oS - oI;
            const size_t so = ((size_t)j * B_N + b) * 3;
            out[so + 0] = oS;
            out[so + 1] = oI;
            out[so + 2] = oR;

            float sm1 = __shfl_up(oS, 1);
            float im1 = __shfl_up(oI, 1);
            if (L == 0) { sm1 = carryS; im1 = carryI; }
            if (j > 0) {
                const float d0 = (oS - sm1) * invdt;
                const float d1 = (oI - im1) * invdt;
                const float d2 = -d0 - d1;
                const size_t dofs = ((size_t)(j - 1) * B_N + b) * 3;
                diff[dofs + 0] = d0;
                diff[dofs + 1] = d1;
                diff[dofs + 2] = d2;
            }
            carryS = rdlane_i(oS, 63);
            carryI = rdlane_i(oI, 63);
        } else if (c < 15) {
            // history dot for chunk c+1 over tau < 64c (R5 layout, unchanged)
            const int w    = wid - 1;
            const int G    = 8 * c;
            const int idx0 = (T_N - 64 * (c + 1)) - R8;
            float p0 = 0.0f, p1 = 0.0f;
            int s = w;
            for (; s + NDW < G; s += 2 * NDW) {
                const h8_t mv0 = *(const h8_t*)&sMeH[idx0 + 8 * s];
                const h8_t iv0 = *(const h8_t*)&sIhR[iofs + 8 * s];
                const h8_t mv1 = *(const h8_t*)&sMeH[idx0 + 8 * (s + NDW)];
                const h8_t iv1 = *(const h8_t*)&sIhR[iofs + 8 * (s + NDW)];
                DOT8(p0, mv0, iv0)
                DOT8(p1, mv1, iv1)
            }
            if (s < G) {
                const h8_t mv0 = *(const h8_t*)&sMeH[idx0 + 8 * s];
                const h8_t iv0 = *(const h8_t*)&sIhR[iofs + 8 * s];
                DOT8(p0, mv0, iv0)
            }
            float p = p0 + p1;
            if (w == 0) {
                // tail fixup: tau = 64c - d, d = 1..f
#pragma unroll
                for (int d = 1; d <= 7; ++d) {
                    const float ih = (float)sIhR[8 + 64 * c - d];   // row 0
                    if (d <= f) p = fmaf(mf[d - 1], ih, p);
                }
            }
            P[(c + 1) & 1][w][L] = p;
        }
        __syncthreads();
    }
#undef STEPB
#undef STEP_GE1
}

// ---------------------------------------------------------------------------
// Launcher
// ---------------------------------------------------------------------------
extern "C" void kernel_launch(void* const* d_in, const int* in_sizes, int n_in,
                              void* d_out, int out_size, void* d_ws, size_t ws_size,
                              hipStream_t stream) {
    const float* t     = (const float*)d_in[0];
    const float* y     = (const float*)d_in[1];
    const float* w1    = (const float*)d_in[2];
    const float* b1    = (const float*)d_in[3];
    const float* w2    = (const float*)d_in[4];
    const float* b2    = (const float*)d_in[5];
    const float* w3    = (const float*)d_in[6];
    const float* b3    = (const float*)d_in[7];
    const float* w4    = (const float*)d_in[8];
    const float* b4    = (const float*)d_in[9];
    const float* beta  = (const float*)d_in[10];
    const float* gamma = (const float*)d_in[11];

    scan_kernel<<<B_N, 512, 0, stream>>>(t, y, w1, b1, w2, b2, w3, b3, w4, b4,
                                         beta, gamma, (float*)d_out);
}

// Round 10
// 124.381 us; speedup vs baseline: 1.0699x; 1.0699x over previous
//
#include <hip/hip_runtime.h>

// Problem constants: T=1024, B=256, H=20
#define T_N 1024
#define B_N 256
#define H_N 20
#define NW  8            // waves per block
#define NDW (NW - 1)     // dot waves
#define SIH 1096         // I-history row stride in HALVES (conflict-free layout, see R5)

typedef _Float16 h8_t __attribute__((ext_vector_type(8)));

#if __has_builtin(__builtin_amdgcn_fdot2)
#define DOT8(acc, mv, iv)                                                           \
    acc = __builtin_amdgcn_fdot2(__builtin_shufflevector(mv, mv, 0, 1),             \
                                 __builtin_shufflevector(iv, iv, 0, 1), acc, false);\
    acc = __builtin_amdgcn_fdot2(__builtin_shufflevector(mv, mv, 2, 3),             \
                                 __builtin_shufflevector(iv, iv, 2, 3), acc, false);\
    acc = __builtin_amdgcn_fdot2(__builtin_shufflevector(mv, mv, 4, 5),             \
                                 __builtin_shufflevector(iv, iv, 4, 5), acc, false);\
    acc = __builtin_amdgcn_fdot2(__builtin_shufflevector(mv, mv, 6, 7),             \
                                 __builtin_shufflevector(iv, iv, 6, 7), acc, false);
#else
#define DOT8(acc, mv, iv)                                                           \
    _Pragma("unroll")                                                               \
    for (int _k = 0; _k < 8; ++_k) acc = fmaf((float)mv[_k], (float)iv[_k], acc);
#endif

__device__ __forceinline__ float rdlane_i(float v, int lane) {
    return __uint_as_float((unsigned)__builtin_amdgcn_readlane((int)__float_as_uint(v), lane));
}
__device__ __forceinline__ float fast_tanh(float x) {
    const float e = __expf(2.0f * x);
    return fmaf(-2.0f, __builtin_amdgcn_rcpf(e + 1.0f), 1.0f);
}
__device__ __forceinline__ float fast_sigmoid(float x) {
    return __builtin_amdgcn_rcpf(1.0f + __expf(-x));
}

// (m, m & 7) literal pairs
#define REPS(F) \
    F(0,0) F(1,1) F(2,2) F(3,3) F(4,4) F(5,5) F(6,6) F(7,7) \
    F(8,0) F(9,1) F(10,2) F(11,3) F(12,4) F(13,5) F(14,6) F(15,7) \
    F(16,0) F(17,1) F(18,2) F(19,3) F(20,4) F(21,5) F(22,6) F(23,7) \
    F(24,0) F(25,1) F(26,2) F(27,3) F(28,4) F(29,5) F(30,6) F(31,7) \
    F(32,0) F(33,1) F(34,2) F(35,3) F(36,4) F(37,5) F(38,6) F(39,7) \
    F(40,0) F(41,1) F(42,2) F(43,3) F(44,4) F(45,5) F(46,6) F(47,7) \
    F(48,0) F(49,1) F(50,2) F(51,3) F(52,4) F(53,5) F(54,6) F(55,7) \
    F(56,0) F(57,1) F(58,2) F(59,3) F(60,4) F(61,5) F(62,6) F(63,7)

// ---------------------------------------------------------------------------
// Single fused kernel. 256 blocks (1/batch) x 512 threads (8 waves).
// Phase A: all waves compute me[1024] -> fp32 sMeF + fp16 sMeH + window sQ.
// Phase B: wave 0 = serial SIR chain. Fold weights stream from the tiny LDS
//          window sQ via per-step static-offset ds_reads, prefetched 8 steps
//          ahead into 16 named rotating registers -> 1 deferred readlane is
//          the only cross-lane op per step.
//          waves 1-7 = fp16 fdot2 history dots (conflict-free R5 layout).
// ---------------------------------------------------------------------------
__global__ __launch_bounds__(512, 1) void scan_kernel(
    const float* __restrict__ t,
    const float* __restrict__ y,
    const float* __restrict__ w1, const float* __restrict__ b1,
    const float* __restrict__ w2, const float* __restrict__ b2,
    const float* __restrict__ w3, const float* __restrict__ b3,
    const float* __restrict__ w4, const float* __restrict__ b4,
    const float* __restrict__ beta_p,
    const float* __restrict__ gamma_p,
    float* __restrict__ out)     // [solution (T*B*3) | diff (T*B*3)]
{
    __shared__ __align__(16) float    sMeF[T_N];      // fp32 me
    __shared__ __align__(16) _Float16 sMeH[T_N];      // fp16 me (dot operand A)
    __shared__ __align__(16) _Float16 sIhR[8 * SIH];  // 8 shifted fp16 I-history rows
    __shared__ __align__(16) float    sQ[192];        // weight window: Q[u]=me_pad[T-128+u]
    __shared__ float P[2][NDW][64];

    const int b   = blockIdx.x;
    const int tid = threadIdx.x;
    const int wid = tid >> 6;
    const int L   = tid & 63;

    // per-lane dot-geometry constants (chunk-invariant)
    const int f    = (-L) & 7;            // misalignment of lane L's me window
    const int R8   = L + f;               // L rounded up to multiple of 8
    const int row  = L & 7;               // I-history row for this lane
    const int iofs = row * SIH + (f ? 0 : 8);

    // zero the row front-pads (slots representing I[<0]) and sQ zero tail
    if (tid < 64) {
        sIhR[(tid >> 3) * SIH + (tid & 7)] = (_Float16)0.0f;
        sQ[128 + tid] = 0.0f;
    }

    // ---- Phase A: me MLP (2 values/thread) ----
#pragma unroll
    for (int v = 0; v < 2; ++v) {
        const int mi = tid + v * 512;
        const float x = t[mi];

        float h1[H_N], h2[H_N];
#pragma unroll
        for (int k = 0; k < H_N; ++k) h1[k] = fast_tanh(fmaf(x, w1[k], b1[k]));

#pragma unroll 4
        for (int k = 0; k < H_N; ++k) {
            float a = b2[k];
#pragma unroll
            for (int j = 0; j < H_N; ++j) a = fmaf(h1[j], w2[j * H_N + k], a);
            h2[k] = fast_tanh(a);
        }

        float a4 = b4[0];
#pragma unroll 4
        for (int k = 0; k < H_N; ++k) {
            float a = b3[k];
#pragma unroll
            for (int j = 0; j < H_N; ++j) a = fmaf(h2[j], w3[j * H_N + k], a);
            a4 = fmaf(fast_tanh(a), w4[k], a4);
        }

        const float meval = fast_sigmoid(a4);
        sMeF[mi] = meval;
        sMeH[mi] = (_Float16)meval;
        if (mi >= T_N - 128) sQ[mi - (T_N - 128)] = meval;
    }

    // ---- scalars / state ----
    const float dt    = t[0] - t[1];
    const float beta  = beta_p[0];
    const float gma   = gamma_p[0];
    const float invdt = 1.0f / dt;

    const float S0 = y[b * 3 + 0];
    const float I0 = y[b * 3 + 1];
    const float R0 = y[b * 3 + 2];
    const float TOT = S0 + I0 + R0;     // SIR total conserved

    // publish I[0] into all 8 rows
    if (tid < 8) sIhR[tid * SIH + 8 - tid] = (_Float16)I0;

    float* __restrict__ diff = out + (size_t)T_N * B_N * 3;
    if (tid < 3) diff[((size_t)(T_N - 1) * B_N + b) * 3 + tid] = 0.0f;

    __syncthreads();   // sMeF/sMeH/sQ/pads/I0 visible

    // fixup me weights (chunk-invariant): mf[d-1] = me[960 - L - d]
    float mf[7];
#pragma unroll
    for (int d = 1; d <= 7; ++d) mf[d - 1] = sMeF[T_N - 64 - L - d];

    const float dtb  = dt * beta;
    const float ndtg = -dt * gma;
    const float dt2  = dt * dt;
    const float meT1 = sMeF[T_N - 1];

    float S = S0, I = I0, oS = S0, oI = I0;
    float acc_cur = 0.0f, acc_nxt = 0.0f, pre = 0.0f;
    float carryS = S0, carryI = I0;

    // weight-window base indices for this lane (compile-time offsets added per step)
    const float* __restrict__ qN = &sQ[64 - L];    // wN(m) = qN[m] = me[T-64-L+m]
    const float* __restrict__ qC = &sQ[128 - L];   // wC(m) = qC[m] = me_pad[T-L+m]

    // 16 named rotating prefetch registers (slot = m & 7)
#define PFDECL(s) float wN_##s, wC_##s;
    PFDECL(0) PFDECL(1) PFDECL(2) PFDECL(3) PFDECL(4) PFDECL(5) PFDECL(6) PFDECL(7)
#undef PFDECL
    if (wid == 0) {
#define PFINIT(s) wN_##s = qN[s]; wC_##s = qC[s];
        PFINIT(0) PFINIT(1) PFINIT(2) PFINIT(3) PFINIT(4) PFINIT(5) PFINIT(6) PFINIT(7)
#undef PFINIT
    }

    // serial step M_: entering (S,I) = y_{64c+M_-1}; produces y_{64c+M_}.
    // pre was read BEFORE step (M_-1)'s fold -> patch with meT1*I (uniform).
#define STEPB(M_, S_, FIRST_)                                           \
    {                                                                   \
        const float sum = (FIRST_) ? pre : fmaf(meT1, I, pre);          \
        float pnx = pre;                                                \
        if ((M_) < 63) pnx = rdlane_i(acc_cur, (M_) + 1);               \
        const float bI = dtb * I;                                       \
        const float i1 = fmaf(ndtg, I, I);                              \
        const float q  = bI * S;                                        \
        const float s1 = S - q;                                         \
        S = fmaf(dt2, sum, s1);                                         \
        I = i1 + q;                                                     \
        const bool cap = (L == (M_));                                   \
        oS = cap ? S : oS;                                              \
        oI = cap ? I : oI;                                              \
        acc_cur = fmaf(wC_##S_, I, acc_cur);                            \
        acc_nxt = fmaf(wN_##S_, I, acc_nxt);                            \
        wN_##S_ = qN[((M_) + 8) & 63];                                  \
        wC_##S_ = qC[((M_) + 8) & 63];                                  \
        pre = pnx;                                                      \
    }
#define STEP_GE1(M_, S_) if ((M_) >= 1) STEPB(M_, S_, false)
#define STEP_GE2(M_, S_) if ((M_) >= 2) STEPB(M_, S_, false)

    for (int c = 0; c < 16; ++c) {
        if (wid == 0) {
            if (c == 0) {
                // fold m=0 (initial I0); lane0's wC_0 is the 0 pad; refill slot 0
                acc_cur = wC_0 * I;
                acc_nxt = wN_0 * I;
                pre = rdlane_i(acc_cur, 1);
                wN_0 = qN[8];
                wC_0 = qC[8];
                STEPB(1, 1, true)
                REPS(STEP_GE2)
            } else {
                float ac = acc_nxt;
#pragma unroll
                for (int w = 0; w < NDW; ++w) ac += P[c & 1][w][L];
                acc_cur = ac;
                acc_nxt = 0.0f;
                pre = rdlane_i(acc_cur, 0);
                STEPB(0, 0, true)
                REPS(STEP_GE1)
            }

            // ---- chunk epilogue (wave 0) ----
            const int j = 64 * c + L;
            const _Float16 hI = (_Float16)oI;
#pragma unroll
            for (int r = 0; r < 8; ++r) sIhR[r * SIH + 8 + (j - r)] = hI;

            const float oR = TOT - oS - oI;
            const size_t so = ((size_t)j * B_N + b) * 3;
            out[so + 0] = oS;
            out[so + 1] = oI;
            out[so + 2] = oR;

            float sm1 = __shfl_up(oS, 1);
            float im1 = __shfl_up(oI, 1);
            if (L == 0) { sm1 = carryS; im1 = carryI; }
            if (j > 0) {
                const float d0 = (oS - sm1) * invdt;
                const float d1 = (oI - im1) * invdt;
                const float d2 = -d0 - d1;
                const size_t dofs = ((size_t)(j - 1) * B_N + b) * 3;
                diff[dofs + 0] = d0;
                diff[dofs + 1] = d1;
                diff[dofs + 2] = d2;
            }
            carryS = rdlane_i(oS, 63);
            carryI = rdlane_i(oI, 63);
        } else if (c < 15) {
            // history dot for chunk c+1 over tau < 64c (R5 layout, unchanged)
            const int w    = wid - 1;
            const int G    = 8 * c;
            const int idx0 = (T_N - 64 * (c + 1)) - R8;
            float p0 = 0.0f, p1 = 0.0f;
            int s = w;
            for (; s + NDW < G; s += 2 * NDW) {
                const h8_t mv0 = *(const h8_t*)&sMeH[idx0 + 8 * s];
                const h8_t iv0 = *(const h8_t*)&sIhR[iofs + 8 * s];
                const h8_t mv1 = *(const h8_t*)&sMeH[idx0 + 8 * (s + NDW)];
                const h8_t iv1 = *(const h8_t*)&sIhR[iofs + 8 * (s + NDW)];
                DOT8(p0, mv0, iv0)
                DOT8(p1, mv1, iv1)
            }
            if (s < G) {
                const h8_t mv0 = *(const h8_t*)&sMeH[idx0 + 8 * s];
                const h8_t iv0 = *(const h8_t*)&sIhR[iofs + 8 * s];
                DOT8(p0, mv0, iv0)
            }
            float p = p0 + p1;
            if (w == 0) {
                // tail fixup: tau = 64c - d, d = 1..f
#pragma unroll
                for (int d = 1; d <= 7; ++d) {
                    const float ih = (float)sIhR[8 + 64 * c - d];   // row 0
                    if (d <= f) p = fmaf(mf[d - 1], ih, p);
                }
            }
            P[(c + 1) & 1][w][L] = p;
        }
        __syncthreads();
    }
#undef STEPB
#undef STEP_GE1
#undef STEP_GE2
}

// ---------------------------------------------------------------------------
// Launcher
// ---------------------------------------------------------------------------
extern "C" void kernel_launch(void* const* d_in, const int* in_sizes, int n_in,
                              void* d_out, int out_size, void* d_ws, size_t ws_size,
                              hipStream_t stream) {
    const float* t     = (const float*)d_in[0];
    const float* y     = (const float*)d_in[1];
    const float* w1    = (const float*)d_in[2];
    const float* b1    = (const float*)d_in[3];
    const float* w2    = (const float*)d_in[4];
    const float* b2    = (const float*)d_in[5];
    const float* w3    = (const float*)d_in[6];
    const float* b3    = (const float*)d_in[7];
    const float* w4    = (const float*)d_in[8];
    const float* b4    = (const float*)d_in[9];
    const float* beta  = (const float*)d_in[10];
    const float* gamma = (const float*)d_in[11];

    scan_kernel<<<B_N, 512, 0, stream>>>(t, y, w1, b1, w2, b2, w3, b3, w4, b4,
                                         beta, gamma, (float*)d_out);
}